// Round 2
// baseline (1019.434 us; speedup 1.0000x reference)
//
#include <hip/hip_runtime.h>
#include <float.h>

#define K_CB 8192
#define D_DIM 256
#define N_PTS 16384
#define BM 128
#define BN 128
#define BKD 32
#define SPLITK 4
#define TILES_PER_SPLIT ((K_CB / SPLITK) / BN)   // 16

// ---------------------------------------------------------------- ce = ||e||^2
__global__ void ce_kernel(const float* __restrict__ cb, float* __restrict__ ce) {
    int t = threadIdx.x;
    int lane = t & 63, w = t >> 6;
    int r = blockIdx.x * 4 + w;                       // grid 2048 * 4 waves = 8192 rows
    const float4 v = *reinterpret_cast<const float4*>(cb + (size_t)r * D_DIM + lane * 4);
    float s = v.x * v.x + v.y * v.y + v.z * v.z + v.w * v.w;
#pragma unroll
    for (int off = 32; off >= 1; off >>= 1) s += __shfl_down(s, off);
    if (lane == 0) ce[r] = s;
}

// ---------------------------------------------------------------- zn = ||z_n||^2
// point n = b*1024 + hw ; features strided by 1024. Coalesced across threads.
__global__ void zn_kernel(const float* __restrict__ z, float* __restrict__ zn) {
    int p = blockIdx.x * 256 + threadIdx.x;
    int b = p >> 10, hw = p & 1023;
    const float* base = z + (size_t)b * (D_DIM * 1024) + hw;
    float s = 0.f;
#pragma unroll 8
    for (int d = 0; d < D_DIM; ++d) {
        float v = base[(size_t)d * 1024];
        s = fmaf(v, v, s);
    }
    zn[p] = s;   // off-by-ulps vs numpy order is fine: exact-grid-shift invariance
}

// ------------------------------------------------- argmin over codebook (split-K)
// Replicates reference fp32 numerics: dist = fl( fl(A + ce_k) - 2*dot ),
// dot accumulated sequentially over d with fma (matches BLAS sgemm per-element).
// Ties broken toward lowest index at every level (np.argmin semantics).
__global__ __launch_bounds__(256, 3)
void argmin_kernel(const float* __restrict__ z, const float* __restrict__ cb,
                   const float* __restrict__ ce, const float* __restrict__ zn,
                   float* __restrict__ pbest, int* __restrict__ pidx) {
    __shared__ float zs[BKD][BM + 4];   // k-major, pad 132 (16B-aligned rows)
    __shared__ float es[BKD][BN + 4];

    const int t  = threadIdx.x;
    const int tx = t & 15, ty = t >> 4;
    const int mblk = blockIdx.x;          // 0..127  point-tile
    const int kb   = blockIdx.y;          // 0..3    codebook split
    const int n0   = mblk * BM;
    const int b    = n0 >> 10;            // 128 | 1024 -> single image per tile
    const int hw0  = n0 & 1023;
    const float* zb = z + (size_t)b * (D_DIM * 1024) + hw0;

    float A8[8];
#pragma unroll
    for (int i = 0; i < 8; ++i) A8[i] = zn[n0 + ty * 8 + i];

    float best[8];
    int   bidx[8];
#pragma unroll
    for (int i = 0; i < 8; ++i) { best[i] = FLT_MAX; bidx[i] = 0; }

    for (int tile = 0; tile < TILES_PER_SPLIT; ++tile) {
        const int e0 = kb * (K_CB / SPLITK) + tile * BN;
        float acc[8][8];
#pragma unroll
        for (int i = 0; i < 8; ++i)
#pragma unroll
            for (int j = 0; j < 8; ++j) acc[i][j] = 0.f;

        for (int d0 = 0; d0 < D_DIM; d0 += BKD) {
            __syncthreads();
            // ---- stage z tile: 32 d x 128 pts, float4 along points (coalesced)
#pragma unroll
            for (int p = 0; p < 4; ++p) {
                int flat = p * 256 + t;            // 0..1023
                int dl = flat >> 5, q = flat & 31;
                float4 v = *reinterpret_cast<const float4*>(
                    zb + (size_t)(d0 + dl) * 1024 + q * 4);
                *reinterpret_cast<float4*>(&zs[dl][q * 4]) = v;
            }
            // ---- stage e tile transposed to k-major: 128 codes x 32 d
#pragma unroll
            for (int p = 0; p < 4; ++p) {
                int flat = p * 256 + t;            // 0..1023
                int r = flat >> 3, c4 = flat & 7;
                float4 v = *reinterpret_cast<const float4*>(
                    cb + (size_t)(e0 + r) * D_DIM + d0 + c4 * 4);
                es[c4 * 4 + 0][r] = v.x;
                es[c4 * 4 + 1][r] = v.y;
                es[c4 * 4 + 2][r] = v.z;
                es[c4 * 4 + 3][r] = v.w;
            }
            __syncthreads();
            // ---- 8x8 micro-tile FMA (sequential over d: matches BLAS ordering)
#pragma unroll
            for (int k = 0; k < BKD; ++k) {
                float za[8], eb[8];
                *reinterpret_cast<float4*>(&za[0]) = *reinterpret_cast<const float4*>(&zs[k][ty * 8]);
                *reinterpret_cast<float4*>(&za[4]) = *reinterpret_cast<const float4*>(&zs[k][ty * 8 + 4]);
                *reinterpret_cast<float4*>(&eb[0]) = *reinterpret_cast<const float4*>(&es[k][tx * 8]);
                *reinterpret_cast<float4*>(&eb[4]) = *reinterpret_cast<const float4*>(&es[k][tx * 8 + 4]);
#pragma unroll
                for (int i = 0; i < 8; ++i)
#pragma unroll
                    for (int j = 0; j < 8; ++j)
                        acc[i][j] = fmaf(za[i], eb[j], acc[i][j]);
            }
        }
        // ---- min-epilogue, fp32 reference semantics
#pragma unroll
        for (int j = 0; j < 8; ++j) {
            int ent = e0 + tx * 8 + j;
            float cej = ce[ent];
#pragma unroll
            for (int i = 0; i < 8; ++i) {
                float t1 = A8[i] + cej;            // fl(A + ||e||^2)  (rounds to A)
                float s  = t1 - 2.0f * acc[i][j];  // 2*acc exact; one rounding
                if (s < best[i]) { best[i] = s; bidx[i] = ent; }   // strict <: lowest idx on tie
            }
        }
    }

    // ---- cross-thread (tx) reduce via LDS reuse
    __syncthreads();
    float* redv = &zs[0][0];                       // 2048 floats needed, 4224 avail
    int*   redi = reinterpret_cast<int*>(&es[0][0]);
#pragma unroll
    for (int i = 0; i < 8; ++i) {
        redv[tx * BM + ty * 8 + i] = best[i];
        redi[tx * BM + ty * 8 + i] = bidx[i];
    }
    __syncthreads();
    if (t < BM) {
        float bv = redv[t]; int bi = redi[t];
#pragma unroll
        for (int x = 1; x < 16; ++x) {
            float v = redv[x * BM + t]; int ii = redi[x * BM + t];
            if (v < bv || (v == bv && ii < bi)) { bv = v; bi = ii; }
        }
        pbest[kb * N_PTS + n0 + t] = bv;
        pidx [kb * N_PTS + n0 + t] = bi;
    }
}

// ---------------------------------------------------------------- combine splits
__global__ void combine_kernel(const float* __restrict__ pbest, const int* __restrict__ pidx,
                               int* __restrict__ idx_out, float* __restrict__ out1) {
    int n = blockIdx.x * 256 + threadIdx.x;
    float bv = pbest[n]; int bi = pidx[n];
#pragma unroll
    for (int s = 1; s < SPLITK; ++s) {
        float v = pbest[s * N_PTS + n]; int ii = pidx[s * N_PTS + n];
        if (v < bv) { bv = v; bi = ii; }           // strict <: lower split = lower idx on tie
    }
    idx_out[n] = bi;
    out1[n] = (float)bi;
}

// ------------------------------------------- gather z_q, straight-through, loss
__global__ void gather_kernel(const float* __restrict__ z, const float* __restrict__ cb,
                              const int* __restrict__ idx, float* __restrict__ out0,
                              float* __restrict__ acc) {
    int t = threadIdx.x;
    int e4 = blockIdx.x * 256 + t;
    int i = e4 * 4;                                // element index in (B,D,H,W) flat
    int d = (i >> 10) & 255;
    int b = i >> 18;
    int nb = b * 1024 + (i & 1023);                // point index of first lane elem

    float4 zv = *reinterpret_cast<const float4*>(z + i);
    float4 o;
    float ls = 0.f;
    {
        int q = idx[nb + 0]; float e = cb[(size_t)q * D_DIM + d];
        float df = e - zv.x; ls += df * df; o.x = zv.x + df;
    }
    {
        int q = idx[nb + 1]; float e = cb[(size_t)q * D_DIM + d];
        float df = e - zv.y; ls += df * df; o.y = zv.y + df;
    }
    {
        int q = idx[nb + 2]; float e = cb[(size_t)q * D_DIM + d];
        float df = e - zv.z; ls += df * df; o.z = zv.z + df;
    }
    {
        int q = idx[nb + 3]; float e = cb[(size_t)q * D_DIM + d];
        float df = e - zv.w; ls += df * df; o.w = zv.w + df;
    }
    *reinterpret_cast<float4*>(out0 + i) = o;

#pragma unroll
    for (int off = 32; off >= 1; off >>= 1) ls += __shfl_down(ls, off);
    __shared__ float wsum[4];
    int lane = t & 63, w = t >> 6;
    if (lane == 0) wsum[w] = ls;
    __syncthreads();
    if (t == 0) atomicAdd(acc, wsum[0] + wsum[1] + wsum[2] + wsum[3]);
}

__global__ void finalize_kernel(const float* __restrict__ acc, float* __restrict__ out2) {
    out2[0] = 0.25f * acc[0] / 4194304.0f;         // BETA * mean
}

// -----------------------------------------------------------------------------
extern "C" void kernel_launch(void* const* d_in, const int* in_sizes, int n_in,
                              void* d_out, int out_size, void* d_ws, size_t ws_size,
                              hipStream_t stream) {
    const float* z  = (const float*)d_in[0];
    const float* cb = (const float*)d_in[1];
    float* out  = (float*)d_out;
    float* out0 = out;                         // z_q_st : 4194304
    float* out1 = out + 4194304;               // indices: 16384
    float* out2 = out + 4194304 + 16384;       // loss   : 1

    char* ws = (char*)d_ws;
    float* pbest = (float*)(ws);               // 4*16384 fl = 256 KB
    int*   pidx  = (int*)  (ws + 262144);      // 256 KB
    int*   idxb  = (int*)  (ws + 524288);      // 64 KB
    float* ce    = (float*)(ws + 589824);      // 32 KB
    float* zn    = (float*)(ws + 622592);      // 64 KB
    float* acc   = (float*)(ws + 688128);      // 4 B

    hipMemsetAsync(acc, 0, 4, stream);
    ce_kernel<<<K_CB / 4, 256, 0, stream>>>(cb, ce);
    zn_kernel<<<N_PTS / 256, 256, 0, stream>>>(z, zn);
    argmin_kernel<<<dim3(N_PTS / BM, SPLITK), 256, 0, stream>>>(z, cb, ce, zn, pbest, pidx);
    combine_kernel<<<N_PTS / 256, 256, 0, stream>>>(pbest, pidx, idxb, out1);
    gather_kernel<<<(N_PTS * D_DIM / 4) / 256, 256, 0, stream>>>(z, cb, idxb, out0, acc);
    finalize_kernel<<<1, 1, 0, stream>>>(acc, out2);
}

// Round 3
// 645.544 us; speedup vs baseline: 1.5792x; 1.5792x over previous
//
#include <hip/hip_runtime.h>
#include <float.h>

#define K_CB 8192
#define D_DIM 256
#define N_PTS 16384
#define SPLITS 16
#define CPS (K_CB / SPLITS)      // 512 codes per split
#define NT (CPS / 128)           // 4 n-tiles of 128
#define CAND_CAP 96
#define MARGIN 3e-4f

typedef __attribute__((ext_vector_type(8))) short short8;
typedef __attribute__((ext_vector_type(4))) float f32x4;

__device__ __forceinline__ unsigned short f2bf(float x) {
    unsigned int u = __float_as_uint(x);
    u = u + 0x7fffu + ((u >> 16) & 1u);            // RNE
    return (unsigned short)(u >> 16);
}

__device__ __forceinline__ void gload16(const void* g, void* l) {
    __builtin_amdgcn_global_load_lds(
        (const __attribute__((address_space(1))) unsigned int*)g,
        (__attribute__((address_space(3))) unsigned int*)l, 16, 0, 0);
}

// ---------------------------------------------------------------- ce = ||e||^2
__global__ void ce_kernel(const float* __restrict__ cb, float* __restrict__ ce) {
    int t = threadIdx.x;
    int lane = t & 63, w = t >> 6;
    int r = blockIdx.x * 4 + w;
    const float4 v = *reinterpret_cast<const float4*>(cb + (size_t)r * D_DIM + lane * 4);
    float s = v.x * v.x + v.y * v.y + v.z * v.z + v.w * v.w;
#pragma unroll
    for (int off = 32; off >= 1; off >>= 1) s += __shfl_down(s, off);
    if (lane == 0) ce[r] = s;
}

// ---------------------------------------------------------------- zn = ||z_n||^2
__global__ void zn_kernel(const float* __restrict__ z, float* __restrict__ zn) {
    int p = blockIdx.x * 256 + threadIdx.x;
    int b = p >> 10, hw = p & 1023;
    const float* base = z + (size_t)b * (D_DIM * 1024) + hw;
    float s = 0.f;
#pragma unroll 8
    for (int d = 0; d < D_DIM; ++d) {
        float v = base[(size_t)d * 1024];
        s = fmaf(v, v, s);
    }
    zn[p] = s;
}

// ---------------------------------------------------------------- cb -> bf16
__global__ void pack_cb_kernel(const float* __restrict__ cb, unsigned short* __restrict__ cbb) {
    int i = blockIdx.x * 256 + threadIdx.x;          // float4 index
    float4 v = reinterpret_cast<const float4*>(cb)[i];
    ushort4 o = { f2bf(v.x), f2bf(v.y), f2bf(v.z), f2bf(v.w) };
    reinterpret_cast<ushort4*>(cbb)[i] = o;
}

// -------------------------------------------- z (B,D,H,W) -> zT[pt][d] bf16
__global__ void pack_z_kernel(const float* __restrict__ z, unsigned short* __restrict__ zT) {
    __shared__ unsigned short tile[64 * 258];
    int t = threadIdx.x;
    int p0 = blockIdx.x * 64;
    int b = p0 >> 10, hw0 = p0 & 1023;
    const float* zb = z + (size_t)b * (D_DIM * 1024) + hw0;
    int ptl = t & 63, dq = t >> 6;
#pragma unroll 4
    for (int i = 0; i < 64; ++i) {
        int d = dq * 64 + i;
        float v = zb[(size_t)d * 1024 + ptl];        // coalesced over lanes
        tile[ptl * 258 + d] = f2bf(v);
    }
    __syncthreads();
    int pw = t >> 2, c0 = (t & 3) * 64;
    unsigned int* outp = reinterpret_cast<unsigned int*>(zT) + (((size_t)(p0 + pw) * D_DIM + c0) >> 1);
#pragma unroll 8
    for (int i = 0; i < 32; ++i) {
        unsigned int lo = tile[pw * 258 + c0 + 2 * i];
        unsigned int hi = tile[pw * 258 + c0 + 2 * i + 1];
        outp[i] = lo | (hi << 16);
    }
}

// -------------------------------------- MFMA screening: min-track + candidates
__global__ __launch_bounds__(256, 3)
void screen_kernel(const unsigned short* __restrict__ zT, const unsigned short* __restrict__ cbb,
                   const float* __restrict__ ce, int* __restrict__ cnt, int* __restrict__ cand) {
    __shared__ char smA[16384];                      // [128 rows][128 B], XOR-swizzled
    __shared__ char smB[16384];
    __shared__ float pmin[2][128];
    __shared__ float rm_s[128];
    __shared__ float th_s[128];

    const int t = threadIdx.x;
    const int lane = t & 63, w = t >> 6;
    const int wm = w >> 1, wn = w & 1;
    const int m0 = blockIdx.x * 128;
    const int c0s = blockIdx.y * CPS;
    const int g = lane >> 4, r = lane & 15;

    if (t < 128) rm_s[t] = FLT_MAX;

    // staging geometry: slot s=(w*4+q)*64+lane -> LDS row 8*(4w+q)+(lane>>3), byte (lane&7)*16
    const int lrow = lane >> 3;
    const int srcsw = (((lane & 7) ^ (lrow & 7)) << 4);   // pre-swizzled source byte

    for (int nt = 0; nt < NT; ++nt) {
        const int c0 = c0s + nt * 128;
        f32x4 acc[4][4];
#pragma unroll
        for (int m = 0; m < 4; ++m)
#pragma unroll
            for (int n = 0; n < 4; ++n) acc[m][n] = (f32x4){0.f, 0.f, 0.f, 0.f};

        for (int ds = 0; ds < 4; ++ds) {
            __syncthreads();
            const int dby = ds * 128;                // 64 bf16 = 128 B per stage
#pragma unroll
            for (int q = 0; q < 4; ++q) {
                int row = (w * 4 + q) * 8 + lrow;
                gload16((const char*)zT  + (size_t)(m0 + row) * 512 + dby + srcsw,
                        smA + (w * 4 + q) * 1024);
                gload16((const char*)cbb + (size_t)(c0 + row) * 512 + dby + srcsw,
                        smB + (w * 4 + q) * 1024);
            }
            asm volatile("s_waitcnt vmcnt(0)");
            __syncthreads();
#pragma unroll
            for (int kk = 0; kk < 2; ++kk) {
                const int cbo = kk * 64 + g * 16;
                short8 a[4], b[4];
#pragma unroll
                for (int m = 0; m < 4; ++m) {
                    int row = wm * 64 + m * 16 + r;
                    a[m] = *(const short8*)(smA + row * 128 + (cbo ^ ((row & 7) << 4)));
                }
#pragma unroll
                for (int n = 0; n < 4; ++n) {
                    int row = wn * 64 + n * 16 + r;
                    b[n] = *(const short8*)(smB + row * 128 + (cbo ^ ((row & 7) << 4)));
                }
#pragma unroll
                for (int m = 0; m < 4; ++m)
#pragma unroll
                    for (int n = 0; n < 4; ++n)
                        acc[m][n] = __builtin_amdgcn_mfma_f32_16x16x32_bf16(a[m], b[n], acc[m][n], 0, 0, 0);
            }
        }

        // ---- epilogue: approx scores, per-point tile-min, candidate collection
        float ce4[4];
#pragma unroll
        for (int n = 0; n < 4; ++n) ce4[n] = ce[c0 + wn * 64 + n * 16 + r];

#pragma unroll
        for (int m = 0; m < 4; ++m)
#pragma unroll
            for (int reg = 0; reg < 4; ++reg) {
                float v = FLT_MAX;
#pragma unroll
                for (int n = 0; n < 4; ++n)
                    v = fminf(v, ce4[n] - 2.f * acc[m][n][reg]);
                v = fminf(v, __shfl_xor(v, 1));
                v = fminf(v, __shfl_xor(v, 2));
                v = fminf(v, __shfl_xor(v, 4));
                v = fminf(v, __shfl_xor(v, 8));
                if (r == 0) pmin[wn][wm * 64 + m * 16 + g * 4 + reg] = v;
            }
        __syncthreads();
        if (t < 128) {
            float nm = fminf(rm_s[t], fminf(pmin[0][t], pmin[1][t]));
            rm_s[t] = nm;
            th_s[t] = nm + MARGIN;
        }
        __syncthreads();
#pragma unroll
        for (int m = 0; m < 4; ++m)
#pragma unroll
            for (int n = 0; n < 4; ++n)
#pragma unroll
                for (int reg = 0; reg < 4; ++reg) {
                    float s = ce4[n] - 2.f * acc[m][n][reg];
                    int ptl = wm * 64 + m * 16 + g * 4 + reg;
                    if (s <= th_s[ptl]) {
                        int pt = m0 + ptl;
                        int code = c0 + wn * 64 + n * 16 + r;
                        int slot = atomicAdd(&cnt[pt], 1);
                        if (slot < CAND_CAP) cand[pt * CAND_CAP + slot] = code;
                    }
                }
    }
}

// ------------------------------- exact fp32 rescore (reference bit-semantics)
__global__ void rescore_kernel(const float* __restrict__ z, const float* __restrict__ cb,
                               const float* __restrict__ ce, const float* __restrict__ zn,
                               const int* __restrict__ cnt, const int* __restrict__ cand,
                               int* __restrict__ idxb, float* __restrict__ out1) {
    int t = threadIdx.x;
    int lane = t & 63, wv = t >> 6;
    int pt = blockIdx.x * 4 + wv;
    int c = cnt[pt]; if (c > CAND_CAP) c = CAND_CAP;
    int b = pt >> 10, hw = pt & 1023;
    const float* zb = z + (size_t)b * (D_DIM * 1024) + hw;
    float A = zn[pt];
    float best = FLT_MAX; int bidx = 0x7fffffff;
    for (int ci = lane; ci < c; ci += 64) {
        int code = cand[pt * CAND_CAP + ci];
        const float* e = cb + (size_t)code * D_DIM;
        float dot = 0.f;
#pragma unroll 8
        for (int d = 0; d < D_DIM; ++d)
            dot = fmaf(zb[(size_t)d << 10], e[d], dot);   // sequential, matches BLAS
        float t1 = A + ce[code];
        float s = t1 - 2.0f * dot;
        if (s < best || (s == best && code < bidx)) { best = s; bidx = code; }
    }
#pragma unroll
    for (int mk = 1; mk <= 32; mk <<= 1) {
        float ov = __shfl_xor(best, mk);
        int   oi = __shfl_xor(bidx, mk);
        if (ov < best || (ov == best && oi < bidx)) { best = ov; bidx = oi; }
    }
    if (lane == 0) { idxb[pt] = bidx; out1[pt] = (float)bidx; }
}

// ------------------------------------------- gather z_q, straight-through, loss
__global__ void gather_kernel(const float* __restrict__ z, const float* __restrict__ cb,
                              const int* __restrict__ idx, float* __restrict__ out0,
                              float* __restrict__ lsum) {
    int t = threadIdx.x;
    int e4 = blockIdx.x * 256 + t;
    int i = e4 * 4;
    int d = (i >> 10) & 255;
    int b = i >> 18;
    int nb = b * 1024 + (i & 1023);

    float4 zv = *reinterpret_cast<const float4*>(z + i);
    float4 o;
    float ls = 0.f;
    { int q = idx[nb + 0]; float e = cb[(size_t)q * D_DIM + d]; float df = e - zv.x; ls += df * df; o.x = zv.x + df; }
    { int q = idx[nb + 1]; float e = cb[(size_t)q * D_DIM + d]; float df = e - zv.y; ls += df * df; o.y = zv.y + df; }
    { int q = idx[nb + 2]; float e = cb[(size_t)q * D_DIM + d]; float df = e - zv.z; ls += df * df; o.z = zv.z + df; }
    { int q = idx[nb + 3]; float e = cb[(size_t)q * D_DIM + d]; float df = e - zv.w; ls += df * df; o.w = zv.w + df; }
    *reinterpret_cast<float4*>(out0 + i) = o;

#pragma unroll
    for (int off = 32; off >= 1; off >>= 1) ls += __shfl_down(ls, off);
    __shared__ float wsum[4];
    int lane = t & 63, w = t >> 6;
    if (lane == 0) wsum[w] = ls;
    __syncthreads();
    if (t == 0) atomicAdd(lsum, wsum[0] + wsum[1] + wsum[2] + wsum[3]);
}

__global__ void finalize_kernel(const float* __restrict__ lsum, float* __restrict__ out2) {
    out2[0] = 0.25f * lsum[0] / 4194304.0f;
}

// -----------------------------------------------------------------------------
extern "C" void kernel_launch(void* const* d_in, const int* in_sizes, int n_in,
                              void* d_out, int out_size, void* d_ws, size_t ws_size,
                              hipStream_t stream) {
    const float* z  = (const float*)d_in[0];
    const float* cb = (const float*)d_in[1];
    float* out  = (float*)d_out;
    float* out0 = out;
    float* out1 = out + 4194304;
    float* out2 = out + 4194304 + 16384;

    char* ws = (char*)d_ws;
    int*            cnt  = (int*)(ws);                          // 64 KB
    int*            cand = (int*)(ws + 65536);                  // 6 MB (16384*96*4)
    int*            idxb = (int*)(ws + 6356992);                // 64 KB
    float*          ce   = (float*)(ws + 6422528);              // 32 KB
    float*          zn   = (float*)(ws + 6455296);              // 64 KB
    float*          lsum = (float*)(ws + 6520832);              // 64 B pad
    unsigned short* cbb  = (unsigned short*)(ws + 6520896);     // 4 MB
    unsigned short* zT   = (unsigned short*)(ws + 10715200);    // 8 MB

    hipMemsetAsync(cnt, 0, 65536, stream);
    hipMemsetAsync(lsum, 0, 4, stream);
    pack_cb_kernel<<<(K_CB * D_DIM / 4) / 256, 256, 0, stream>>>(cb, cbb);
    pack_z_kernel<<<N_PTS / 64, 256, 0, stream>>>(z, zT);
    ce_kernel<<<K_CB / 4, 256, 0, stream>>>(cb, ce);
    zn_kernel<<<N_PTS / 256, 256, 0, stream>>>(z, zn);
    screen_kernel<<<dim3(N_PTS / 128, SPLITS), 256, 0, stream>>>(zT, cbb, ce, cnt, cand);
    rescore_kernel<<<N_PTS / 4, 256, 0, stream>>>(z, cb, ce, zn, cnt, cand, idxb, out1);
    gather_kernel<<<(N_PTS * D_DIM / 4) / 256, 256, 0, stream>>>(z, cb, idxb, out0, lsum);
    finalize_kernel<<<1, 1, 0, stream>>>(lsum, out2);
}

// Round 5
// 527.364 us; speedup vs baseline: 1.9331x; 1.2241x over previous
//
#include <hip/hip_runtime.h>
#include <float.h>

#define K_CB 8192
#define D_DIM 256
#define N_PTS 16384
#define SPLITS 16
#define CPS (K_CB / SPLITS)      // 512 codes per split-block
#define NTILES 4                 // 128-code n-tiles per block
#define CAND_CAP 96
#define MARGIN 3e-4f
#define FILT   1.2e-4f

typedef __attribute__((ext_vector_type(8))) short short8;
typedef __attribute__((ext_vector_type(4))) float f32x4;

__device__ __forceinline__ unsigned short f2bf(float x) {
    unsigned int u = __float_as_uint(x);
    u = u + 0x7fffu + ((u >> 16) & 1u);            // RNE
    return (unsigned short)(u >> 16);
}

__device__ __forceinline__ void gload16(const void* g, void* l) {
    __builtin_amdgcn_global_load_lds(
        (const __attribute__((address_space(1))) unsigned int*)g,
        (__attribute__((address_space(3))) unsigned int*)l, 16, 0, 0);
}

#define SBAR  __builtin_amdgcn_sched_barrier(0)
#define BARRIER __builtin_amdgcn_s_barrier()
#define WAIT_VM(n) asm volatile("s_waitcnt vmcnt(" #n ")" ::: "memory")
#define WAIT_LGKM0 asm volatile("s_waitcnt lgkmcnt(0)" ::: "memory")

// ---------------------------------------------------------------- ce = ||e||^2
__global__ void ce_kernel(const float* __restrict__ cb, float* __restrict__ ce) {
    int t = threadIdx.x;
    int lane = t & 63, w = t >> 6;
    int r = blockIdx.x * 4 + w;
    const float4 v = *reinterpret_cast<const float4*>(cb + (size_t)r * D_DIM + lane * 4);
    float s = v.x * v.x + v.y * v.y + v.z * v.z + v.w * v.w;
#pragma unroll
    for (int off = 32; off >= 1; off >>= 1) s += __shfl_down(s, off);
    if (lane == 0) ce[r] = s;
}

// ---------------------------------------------------------------- zn = ||z_n||^2
__global__ void zn_kernel(const float* __restrict__ z, float* __restrict__ zn) {
    int p = blockIdx.x * 256 + threadIdx.x;
    int b = p >> 10, hw = p & 1023;
    const float* base = z + (size_t)b * (D_DIM * 1024) + hw;
    float s = 0.f;
#pragma unroll 8
    for (int d = 0; d < D_DIM; ++d) {
        float v = base[(size_t)d * 1024];
        s = fmaf(v, v, s);
    }
    zn[p] = s;
}

// ---------------------------------------------------------------- cb -> bf16
__global__ void pack_cb_kernel(const float* __restrict__ cb, unsigned short* __restrict__ cbb) {
    int i = blockIdx.x * 256 + threadIdx.x;
    float4 v = reinterpret_cast<const float4*>(cb)[i];
    ushort4 o = { f2bf(v.x), f2bf(v.y), f2bf(v.z), f2bf(v.w) };
    reinterpret_cast<ushort4*>(cbb)[i] = o;
}

// -------------------------------------------- z (B,D,H,W) -> zT[pt][d] bf16
__global__ void pack_z_kernel(const float* __restrict__ z, unsigned short* __restrict__ zT) {
    __shared__ unsigned short tile[64 * 258];
    int t = threadIdx.x;
    int p0 = blockIdx.x * 64;
    int b = p0 >> 10, hw0 = p0 & 1023;
    const float* zb = z + (size_t)b * (D_DIM * 1024) + hw0;
    int ptl = t & 63, dq = t >> 6;
#pragma unroll 4
    for (int i = 0; i < 64; ++i) {
        int d = dq * 64 + i;
        float v = zb[(size_t)d * 1024 + ptl];
        tile[ptl * 258 + d] = f2bf(v);
    }
    __syncthreads();
    int pw = t >> 2, c0 = (t & 3) * 64;
    unsigned int* outp = reinterpret_cast<unsigned int*>(zT) + (((size_t)(p0 + pw) * D_DIM + c0) >> 1);
#pragma unroll 8
    for (int i = 0; i < 32; ++i) {
        unsigned int lo = tile[pw * 258 + c0 + 2 * i];
        unsigned int hi = tile[pw * 258 + c0 + 2 * i + 1];
        outp[i] = lo | (hi << 16);
    }
}

// --------------------------- MFMA screening v3: A-resident regs + B pipeline
//                              + block-shared candidate threshold (round-3 stats)
__global__ __launch_bounds__(512, 2)
void screen_kernel(const unsigned short* __restrict__ zT, const unsigned short* __restrict__ cbb,
                   const float* __restrict__ ce, int* __restrict__ cnt,
                   int* __restrict__ candV, float* __restrict__ candS) {
    __shared__ char sm[65536];        // union: A-stage [4][16KB] -> B ring bufs [4][16KB]
    __shared__ float pmin2[2][128];   // per-tile column mins (separate from ring)

    const int t = threadIdx.x;
    const int lane = t & 63, w = t >> 6;          // 8 waves
    const int wm = w >> 1, wn = w & 1;            // 4M x 2N
    const int g = lane >> 4, r = lane & 15;
    const int m0 = blockIdx.x * 128;
    const int c0s = blockIdx.y * CPS;
    const int lrow = lane >> 3;
    const int srcsw = (((lane & 7) ^ (lrow & 7)) << 4);   // pre-swizzled source byte
    const char* zTb = (const char*)zT;
    const char* cbB = (const char*)cbb;

    // ---- preload ce for all epilogues (regs; keeps pipeline free of new loads)
    float ceR[NTILES][4];
#pragma unroll
    for (int nt = 0; nt < NTILES; ++nt)
#pragma unroll
        for (int f = 0; f < 4; ++f)
            ceR[nt][f] = ce[c0s + nt * 128 + wn * 64 + f * 16 + r];

    // ---- stage A (128 pts x 256 d bf16 = 64 KB), linear dest + pre-swz source
#pragma unroll
    for (int dc = 0; dc < 4; ++dc)
#pragma unroll
        for (int q = 0; q < 2; ++q) {
            int row = (w * 2 + q) * 8 + lrow;
            gload16(zTb + (size_t)(m0 + row) * 512 + dc * 128 + srcsw,
                    sm + dc * 16384 + (w * 2 + q) * 1024);
        }
    WAIT_VM(0); SBAR; BARRIER; SBAR;

    // ---- A fragments into registers: a[m][kv], kv = dc*2+kk (64 VGPR)
    short8 a[2][8];
#pragma unroll
    for (int m = 0; m < 2; ++m)
#pragma unroll
        for (int kv = 0; kv < 8; ++kv) {
            int row = wm * 32 + m * 16 + r;
            a[m][kv] = *reinterpret_cast<const short8*>(
                sm + (kv >> 1) * 16384 + row * 128 + (((kv & 1) * 64 + g * 16) ^ ((row & 7) << 4)));
        }
    WAIT_LGKM0; SBAR; BARRIER; SBAR;   // all waves done reading A before B overwrites

#define STAGE_B(s_) do {                                                          \
        int nt_ = (s_) >> 2, dc_ = (s_) & 3;                                      \
        _Pragma("unroll")                                                         \
        for (int q = 0; q < 2; ++q) {                                             \
            int row = (w * 2 + q) * 8 + lrow;                                     \
            gload16(cbB + (size_t)(c0s + nt_ * 128 + row) * 512 + dc_ * 128 + srcsw, \
                    sm + dc_ * 16384 + (w * 2 + q) * 1024);                       \
        }                                                                         \
    } while (0)

    // ---- prologue: 3 stages in flight (6 loads/wave)
    STAGE_B(0); STAGE_B(1); STAGE_B(2);

    float rm[2][4];
#pragma unroll
    for (int m = 0; m < 2; ++m)
#pragma unroll
        for (int reg = 0; reg < 4; ++reg) rm[m][reg] = FLT_MAX;

#pragma unroll
    for (int nt = 0; nt < NTILES; ++nt) {
        f32x4 acc[2][4];
#pragma unroll
        for (int m = 0; m < 2; ++m)
#pragma unroll
            for (int f = 0; f < 4; ++f) acc[m][f] = (f32x4){0.f, 0.f, 0.f, 0.f};

#pragma unroll
        for (int dc = 0; dc < 4; ++dc) {
            const int s = nt * 4 + dc;
            if (s <= 13)      { WAIT_VM(4); }     // counted: the 2 newer stages stay in flight
            else if (s == 14) { WAIT_VM(2); }
            else              { WAIT_VM(0); }
            SBAR; BARRIER; SBAR;
            if (s <= 12) STAGE_B(s + 3);          // refill ring buffer (s-1)&3

            // B fragments from buf dc
            short8 bfr[4][2];
#pragma unroll
            for (int f = 0; f < 4; ++f)
#pragma unroll
                for (int kk = 0; kk < 2; ++kk) {
                    int row = wn * 64 + f * 16 + r;
                    bfr[f][kk] = *reinterpret_cast<const short8*>(
                        sm + dc * 16384 + row * 128 + ((kk * 64 + g * 16) ^ ((row & 7) << 4)));
                }
            WAIT_LGKM0; SBAR;
            __builtin_amdgcn_s_setprio(1);
#pragma unroll
            for (int m = 0; m < 2; ++m)
#pragma unroll
                for (int f = 0; f < 4; ++f)
#pragma unroll
                    for (int kk = 0; kk < 2; ++kk)
                        acc[m][f] = __builtin_amdgcn_mfma_f32_16x16x32_bf16(
                            a[m][dc * 2 + kk], bfr[f][kk], acc[m][f], 0, 0, 0);
            __builtin_amdgcn_s_setprio(0);
        }

        // ---- epilogue: per-point tile-min, BLOCK-SHARED threshold (round-3 stats)
#pragma unroll
        for (int m = 0; m < 2; ++m)
#pragma unroll
            for (int reg = 0; reg < 4; ++reg) {
                float v = FLT_MAX;
#pragma unroll
                for (int f = 0; f < 4; ++f)
                    v = fminf(v, ceR[nt][f] - 2.f * acc[m][f][reg]);
                v = fminf(v, __shfl_xor(v, 1));
                v = fminf(v, __shfl_xor(v, 2));
                v = fminf(v, __shfl_xor(v, 4));
                v = fminf(v, __shfl_xor(v, 8));
                if (r == 0) pmin2[wn][wm * 32 + m * 16 + g * 4 + reg] = v;
            }
        WAIT_LGKM0; SBAR; BARRIER; SBAR;           // publish column mins
#pragma unroll
        for (int m = 0; m < 2; ++m)
#pragma unroll
            for (int reg = 0; reg < 4; ++reg) {
                int ptl = wm * 32 + m * 16 + g * 4 + reg;
                rm[m][reg] = fminf(rm[m][reg], fminf(pmin2[0][ptl], pmin2[1][ptl]));
            }
        // (pmin2 reuse next tile is protected by the next tile's stage barriers)
#pragma unroll
        for (int m = 0; m < 2; ++m)
#pragma unroll
            for (int f = 0; f < 4; ++f)
#pragma unroll
                for (int reg = 0; reg < 4; ++reg) {
                    float s_apx = ceR[nt][f] - 2.f * acc[m][f][reg];
                    if (s_apx <= rm[m][reg] + MARGIN) {
                        int pt = m0 + wm * 32 + m * 16 + g * 4 + reg;
                        int code = c0s + nt * 128 + wn * 64 + f * 16 + r;
                        int slot = atomicAdd(&cnt[pt], 1);
                        if (slot < CAND_CAP) {
                            candV[pt * CAND_CAP + slot] = code;
                            candS[pt * CAND_CAP + slot] = s_apx;
                        }
                    }
                }
    }
#undef STAGE_B
}

// -------------- exact fp32 rescore (reference bit-semantics), approx-filtered,
//                with full-scan fallback on candidate-cap overflow
__global__ void rescore_kernel(const float* __restrict__ z, const float* __restrict__ cb,
                               const float* __restrict__ ce, const float* __restrict__ zn,
                               const int* __restrict__ cnt, const int* __restrict__ candV,
                               const float* __restrict__ candS,
                               int* __restrict__ idxb, float* __restrict__ out1) {
    int t = threadIdx.x;
    int lane = t & 63, wv = t >> 6;
    int pt = blockIdx.x * 4 + wv;
    int craw = cnt[pt];

    int b = pt >> 10, hw = pt & 1023;
    const float* zb = z + (size_t)b * (D_DIM * 1024) + hw;
    float A = zn[pt];
    float best = FLT_MAX; int bidx = 0x7fffffff;

    if (craw > CAND_CAP) {
        // overflow fallback: exact scan of all K codes (unconditional correctness)
        for (int code = lane; code < K_CB; code += 64) {
            const float* e = cb + (size_t)code * D_DIM;
            float dot = 0.f;
#pragma unroll 8
            for (int d = 0; d < D_DIM; ++d)
                dot = fmaf(zb[(size_t)d << 10], e[d], dot);
            float t1 = A + ce[code];
            float s = t1 - 2.0f * dot;
            if (s < best || (s == best && code < bidx)) { best = s; bidx = code; }
        }
    } else {
        int c = craw;
        // phase a: min of approx scores
        float mn = FLT_MAX;
        for (int ci = lane; ci < c; ci += 64) mn = fminf(mn, candS[pt * CAND_CAP + ci]);
#pragma unroll
        for (int mk = 1; mk <= 32; mk <<= 1) mn = fminf(mn, __shfl_xor(mn, mk));
        float filt = mn + FILT;
        // phase b: exact sequential-fma dot only for survivors
        for (int ci = lane; ci < c; ci += 64) {
            float sa = candS[pt * CAND_CAP + ci];
            if (sa <= filt) {
                int code = candV[pt * CAND_CAP + ci];
                const float* e = cb + (size_t)code * D_DIM;
                float dot = 0.f;
#pragma unroll 8
                for (int d = 0; d < D_DIM; ++d)
                    dot = fmaf(zb[(size_t)d << 10], e[d], dot);   // sequential: BLAS order
                float t1 = A + ce[code];
                float s = t1 - 2.0f * dot;
                if (s < best || (s == best && code < bidx)) { best = s; bidx = code; }
            }
        }
    }
#pragma unroll
    for (int mk = 1; mk <= 32; mk <<= 1) {
        float ov = __shfl_xor(best, mk);
        int   oi = __shfl_xor(bidx, mk);
        if (ov < best || (ov == best && oi < bidx)) { best = ov; bidx = oi; }
    }
    if (lane == 0) { idxb[pt] = bidx; out1[pt] = (float)bidx; }
}

// ------------------------------------------- gather z_q, straight-through, loss
__global__ void gather_kernel(const float* __restrict__ z, const float* __restrict__ cb,
                              const int* __restrict__ idx, float* __restrict__ out0,
                              float* __restrict__ lsum) {
    int t = threadIdx.x;
    int e4 = blockIdx.x * 256 + t;
    int i = e4 * 4;
    int d = (i >> 10) & 255;
    int b = i >> 18;
    int nb = b * 1024 + (i & 1023);

    float4 zv = *reinterpret_cast<const float4*>(z + i);
    float4 o;
    float ls = 0.f;
    { int q = idx[nb + 0]; float e = cb[(size_t)q * D_DIM + d]; float df = e - zv.x; ls += df * df; o.x = zv.x + df; }
    { int q = idx[nb + 1]; float e = cb[(size_t)q * D_DIM + d]; float df = e - zv.y; ls += df * df; o.y = zv.y + df; }
    { int q = idx[nb + 2]; float e = cb[(size_t)q * D_DIM + d]; float df = e - zv.z; ls += df * df; o.z = zv.z + df; }
    { int q = idx[nb + 3]; float e = cb[(size_t)q * D_DIM + d]; float df = e - zv.w; ls += df * df; o.w = zv.w + df; }
    *reinterpret_cast<float4*>(out0 + i) = o;

#pragma unroll
    for (int off = 32; off >= 1; off >>= 1) ls += __shfl_down(ls, off);
    __shared__ float wsum[4];
    int lane = t & 63, w = t >> 6;
    if (lane == 0) wsum[w] = ls;
    __syncthreads();
    if (t == 0) atomicAdd(lsum, wsum[0] + wsum[1] + wsum[2] + wsum[3]);
}

__global__ void finalize_kernel(const float* __restrict__ lsum, float* __restrict__ out2) {
    out2[0] = 0.25f * lsum[0] / 4194304.0f;
}

// -----------------------------------------------------------------------------
extern "C" void kernel_launch(void* const* d_in, const int* in_sizes, int n_in,
                              void* d_out, int out_size, void* d_ws, size_t ws_size,
                              hipStream_t stream) {
    const float* z  = (const float*)d_in[0];
    const float* cb = (const float*)d_in[1];
    float* out  = (float*)d_out;
    float* out0 = out;
    float* out1 = out + 4194304;
    float* out2 = out + 4194304 + 16384;

    char* ws = (char*)d_ws;
    int*            cnt   = (int*)(ws);                          // 64 KB
    int*            candV = (int*)(ws + 65536);                  // 6 MB
    float*          candS = (float*)(ws + 6356992);              // 6 MB
    int*            idxb  = (int*)(ws + 12648448);               // 64 KB
    float*          ce    = (float*)(ws + 12713984);             // 32 KB
    float*          zn    = (float*)(ws + 12746752);             // 64 KB
    float*          lsum  = (float*)(ws + 12812288);             // 64 B
    unsigned short* cbb   = (unsigned short*)(ws + 12812352);    // 4 MB
    unsigned short* zT    = (unsigned short*)(ws + 17006656);    // 8 MB

    hipMemsetAsync(cnt, 0, 65536, stream);
    hipMemsetAsync(lsum, 0, 4, stream);
    pack_cb_kernel<<<(K_CB * D_DIM / 4) / 256, 256, 0, stream>>>(cb, cbb);
    pack_z_kernel<<<N_PTS / 64, 256, 0, stream>>>(z, zT);
    ce_kernel<<<K_CB / 4, 256, 0, stream>>>(cb, ce);
    zn_kernel<<<N_PTS / 256, 256, 0, stream>>>(z, zn);
    screen_kernel<<<dim3(N_PTS / 128, SPLITS), 512, 0, stream>>>(zT, cbb, ce, cnt, candV, candS);
    rescore_kernel<<<N_PTS / 4, 256, 0, stream>>>(z, cb, ce, zn, cnt, candV, candS, idxb, out1);
    gather_kernel<<<(N_PTS * D_DIM / 4) / 256, 256, 0, stream>>>(z, cb, idxb, out0, lsum);
    finalize_kernel<<<1, 1, 0, stream>>>(lsum, out2);
}

// Round 6
// 502.527 us; speedup vs baseline: 2.0286x; 1.0494x over previous
//
#include <hip/hip_runtime.h>
#include <float.h>

#define K_CB 8192
#define D_DIM 256
#define N_PTS 16384
#define SPLITS 16
#define CPS (K_CB / SPLITS)      // 512 codes per split-block
#define NTILES 4                 // 128-code n-tiles per block
#define CAND_CAP 96
#define CBUF_CAP 1536
#define MARGIN 3e-4f
#define FILT   1.2e-4f

typedef __attribute__((ext_vector_type(8))) short short8;
typedef __attribute__((ext_vector_type(4))) float f32x4;

__device__ __forceinline__ unsigned short f2bf(float x) {
    unsigned int u = __float_as_uint(x);
    u = u + 0x7fffu + ((u >> 16) & 1u);            // RNE
    return (unsigned short)(u >> 16);
}

__device__ __forceinline__ void gload16(const void* g, void* l) {
    __builtin_amdgcn_global_load_lds(
        (const __attribute__((address_space(1))) unsigned int*)g,
        (__attribute__((address_space(3))) unsigned int*)l, 16, 0, 0);
}

#define SBAR  __builtin_amdgcn_sched_barrier(0)
#define BARRIER __builtin_amdgcn_s_barrier()
#define WAIT_VM(n) asm volatile("s_waitcnt vmcnt(" #n ")" ::: "memory")
#define WAIT_LGKM0 asm volatile("s_waitcnt lgkmcnt(0)" ::: "memory")

// ---------------------------------------------------------------- ce = ||e||^2
__global__ void ce_kernel(const float* __restrict__ cb, float* __restrict__ ce) {
    int t = threadIdx.x;
    int lane = t & 63, w = t >> 6;
    int r = blockIdx.x * 4 + w;
    const float4 v = *reinterpret_cast<const float4*>(cb + (size_t)r * D_DIM + lane * 4);
    float s = v.x * v.x + v.y * v.y + v.z * v.z + v.w * v.w;
#pragma unroll
    for (int off = 32; off >= 1; off >>= 1) s += __shfl_down(s, off);
    if (lane == 0) ce[r] = s;
}

// ---------------------------------------------------------------- zn = ||z_n||^2
__global__ void zn_kernel(const float* __restrict__ z, float* __restrict__ zn) {
    int p = blockIdx.x * 256 + threadIdx.x;
    int b = p >> 10, hw = p & 1023;
    const float* base = z + (size_t)b * (D_DIM * 1024) + hw;
    float s = 0.f;
#pragma unroll 8
    for (int d = 0; d < D_DIM; ++d) {
        float v = base[(size_t)d * 1024];
        s = fmaf(v, v, s);
    }
    zn[p] = s;
}

// ---------------------------------------------------------------- cb -> bf16
__global__ void pack_cb_kernel(const float* __restrict__ cb, unsigned short* __restrict__ cbb) {
    int i = blockIdx.x * 256 + threadIdx.x;
    float4 v = reinterpret_cast<const float4*>(cb)[i];
    ushort4 o = { f2bf(v.x), f2bf(v.y), f2bf(v.z), f2bf(v.w) };
    reinterpret_cast<ushort4*>(cbb)[i] = o;
}

// -------------------------------------------- z (B,D,H,W) -> zT[pt][d] bf16
__global__ void pack_z_kernel(const float* __restrict__ z, unsigned short* __restrict__ zT) {
    __shared__ unsigned short tile[64 * 258];
    int t = threadIdx.x;
    int p0 = blockIdx.x * 64;
    int b = p0 >> 10, hw0 = p0 & 1023;
    const float* zb = z + (size_t)b * (D_DIM * 1024) + hw0;
    int ptl = t & 63, dq = t >> 6;
#pragma unroll 4
    for (int i = 0; i < 64; ++i) {
        int d = dq * 64 + i;
        float v = zb[(size_t)d * 1024 + ptl];
        tile[ptl * 258 + d] = f2bf(v);
    }
    __syncthreads();
    int pw = t >> 2, c0 = (t & 3) * 64;
    unsigned int* outp = reinterpret_cast<unsigned int*>(zT) + (((size_t)(p0 + pw) * D_DIM + c0) >> 1);
#pragma unroll 8
    for (int i = 0; i < 32; ++i) {
        unsigned int lo = tile[pw * 258 + c0 + 2 * i];
        unsigned int hi = tile[pw * 258 + c0 + 2 * i + 1];
        outp[i] = lo | (hi << 16);
    }
}

// --------------------------- MFMA screening v4: A-resident regs + B pipeline
//  + block-shared threshold (validated r3/r5 stats)
//  + LDS candidate staging (K-loop VMEM = staging loads ONLY -> counted vmcnt valid)
__global__ __launch_bounds__(512, 4)
void screen_kernel(const unsigned short* __restrict__ zT, const unsigned short* __restrict__ cbb,
                   const float* __restrict__ ce, int* __restrict__ cnt,
                   int* __restrict__ candV, float* __restrict__ candS) {
    __shared__ char sm[65536];        // union: A-stage [4][16KB] -> B ring bufs [4][16KB]
    __shared__ float pmin2[2][128];   // per-tile column mins
    __shared__ uint2 cbuf[CBUF_CAP];  // candidate staging: (ptl<<16|code, score-bits)
    __shared__ int ccnt;

    const int t = threadIdx.x;
    const int lane = t & 63, w = t >> 6;          // 8 waves
    const int wm = w >> 1, wn = w & 1;            // 4M x 2N
    const int g = lane >> 4, r = lane & 15;
    const int m0 = blockIdx.x * 128;
    const int c0s = blockIdx.y * CPS;
    const int lrow = lane >> 3;
    const int srcsw = (((lane & 7) ^ (lrow & 7)) << 4);   // pre-swizzled source byte
    const char* zTb = (const char*)zT;
    const char* cbB = (const char*)cbb;

    if (t == 0) ccnt = 0;

    // ---- preload ce for all epilogues (regs; keeps pipeline free of new loads)
    float ceR[NTILES][4];
#pragma unroll
    for (int nt = 0; nt < NTILES; ++nt)
#pragma unroll
        for (int f = 0; f < 4; ++f)
            ceR[nt][f] = ce[c0s + nt * 128 + wn * 64 + f * 16 + r];

    // ---- stage A (128 pts x 256 d bf16 = 64 KB), linear dest + pre-swz source
#pragma unroll
    for (int dc = 0; dc < 4; ++dc)
#pragma unroll
        for (int q = 0; q < 2; ++q) {
            int row = (w * 2 + q) * 8 + lrow;
            gload16(zTb + (size_t)(m0 + row) * 512 + dc * 128 + srcsw,
                    sm + dc * 16384 + (w * 2 + q) * 1024);
        }
    WAIT_VM(0);
    __syncthreads();                   // also fences the ccnt init

    // ---- A fragments into registers: a[m][kv], kv = dc*2+kk (64 VGPR)
    short8 a[2][8];
#pragma unroll
    for (int m = 0; m < 2; ++m)
#pragma unroll
        for (int kv = 0; kv < 8; ++kv) {
            int row = wm * 32 + m * 16 + r;
            a[m][kv] = *reinterpret_cast<const short8*>(
                sm + (kv >> 1) * 16384 + row * 128 + (((kv & 1) * 64 + g * 16) ^ ((row & 7) << 4)));
        }
    WAIT_LGKM0; SBAR; BARRIER; SBAR;   // all waves done reading A before B overwrites

#define STAGE_B(s_) do {                                                          \
        int nt_ = (s_) >> 2, dc_ = (s_) & 3;                                      \
        _Pragma("unroll")                                                         \
        for (int q = 0; q < 2; ++q) {                                             \
            int row = (w * 2 + q) * 8 + lrow;                                     \
            gload16(cbB + (size_t)(c0s + nt_ * 128 + row) * 512 + dc_ * 128 + srcsw, \
                    sm + dc_ * 16384 + (w * 2 + q) * 1024);                       \
        }                                                                         \
    } while (0)

    // ---- prologue: 3 stages in flight (6 loads/wave)
    STAGE_B(0); STAGE_B(1); STAGE_B(2);

    float rm[2][4];
#pragma unroll
    for (int m = 0; m < 2; ++m)
#pragma unroll
        for (int reg = 0; reg < 4; ++reg) rm[m][reg] = FLT_MAX;

#pragma unroll
    for (int nt = 0; nt < NTILES; ++nt) {
        f32x4 acc[2][4];
#pragma unroll
        for (int m = 0; m < 2; ++m)
#pragma unroll
            for (int f = 0; f < 4; ++f) acc[m][f] = (f32x4){0.f, 0.f, 0.f, 0.f};

#pragma unroll
        for (int dc = 0; dc < 4; ++dc) {
            const int s = nt * 4 + dc;
            if (s <= 13)      { WAIT_VM(4); }     // counted: 2 newer stages stay in flight
            else if (s == 14) { WAIT_VM(2); }
            else              { WAIT_VM(0); }
            SBAR; BARRIER; SBAR;
            if (s <= 12) STAGE_B(s + 3);          // refill ring buffer (s-1)&3

            // B fragments from buf dc
            short8 bfr[4][2];
#pragma unroll
            for (int f = 0; f < 4; ++f)
#pragma unroll
                for (int kk = 0; kk < 2; ++kk) {
                    int row = wn * 64 + f * 16 + r;
                    bfr[f][kk] = *reinterpret_cast<const short8*>(
                        sm + dc * 16384 + row * 128 + ((kk * 64 + g * 16) ^ ((row & 7) << 4)));
                }
            WAIT_LGKM0; SBAR;
            __builtin_amdgcn_s_setprio(1);
#pragma unroll
            for (int m = 0; m < 2; ++m)
#pragma unroll
                for (int f = 0; f < 4; ++f)
#pragma unroll
                    for (int kk = 0; kk < 2; ++kk)
                        acc[m][f] = __builtin_amdgcn_mfma_f32_16x16x32_bf16(
                            a[m][dc * 2 + kk], bfr[f][kk], acc[m][f], 0, 0, 0);
            __builtin_amdgcn_s_setprio(0);
        }

        // ---- epilogue: per-point tile-min, block-shared threshold (r3/r5 stats)
#pragma unroll
        for (int m = 0; m < 2; ++m)
#pragma unroll
            for (int reg = 0; reg < 4; ++reg) {
                float v = FLT_MAX;
#pragma unroll
                for (int f = 0; f < 4; ++f)
                    v = fminf(v, ceR[nt][f] - 2.f * acc[m][f][reg]);
                v = fminf(v, __shfl_xor(v, 1));
                v = fminf(v, __shfl_xor(v, 2));
                v = fminf(v, __shfl_xor(v, 4));
                v = fminf(v, __shfl_xor(v, 8));
                if (r == 0) pmin2[wn][wm * 32 + m * 16 + g * 4 + reg] = v;
            }
        WAIT_LGKM0; SBAR; BARRIER; SBAR;           // publish column mins
        float th[2][4];
#pragma unroll
        for (int m = 0; m < 2; ++m)
#pragma unroll
            for (int reg = 0; reg < 4; ++reg) {
                int ptl = wm * 32 + m * 16 + g * 4 + reg;
                rm[m][reg] = fminf(rm[m][reg], fminf(pmin2[0][ptl], pmin2[1][ptl]));
                th[m][reg] = rm[m][reg] + MARGIN;
            }
        // ---- collection into LDS staging (DS ops only: vmcnt untouched)
#pragma unroll
        for (int m = 0; m < 2; ++m)
#pragma unroll
            for (int f = 0; f < 4; ++f)
#pragma unroll
                for (int reg = 0; reg < 4; ++reg) {
                    float s_apx = ceR[nt][f] - 2.f * acc[m][f][reg];
                    if (s_apx <= th[m][reg]) {
                        int ptl = wm * 32 + m * 16 + g * 4 + reg;
                        int code = c0s + nt * 128 + wn * 64 + f * 16 + r;
                        int slot = atomicAdd(&ccnt, 1);
                        if (slot < CBUF_CAP)
                            cbuf[slot] = make_uint2(((unsigned)ptl << 16) | (unsigned)code,
                                                    __float_as_uint(s_apx));
                    }
                }
    }
#undef STAGE_B

    // ---- bulk flush to global (vmcnt-clean; after all pipelined stages)
    WAIT_LGKM0;
    __syncthreads();
    int total = ccnt;
    if (total > CBUF_CAP) {
        if (t < 128) atomicAdd(&cnt[m0 + t], 1000);    // poison -> full-scan fallback
    } else {
        for (int i = t; i < total; i += 512) {
            uint2 e = cbuf[i];
            int pt = m0 + (int)(e.x >> 16);
            int code = (int)(e.x & 0xffffu);
            int slot = atomicAdd(&cnt[pt], 1);
            if (slot < CAND_CAP) {
                candV[pt * CAND_CAP + slot] = code;
                candS[pt * CAND_CAP + slot] = __uint_as_float(e.y);
            }
        }
    }
}

// -------------- exact fp32 rescore (reference bit-semantics), approx-filtered,
//                with full-scan fallback on candidate-cap overflow
__global__ void rescore_kernel(const float* __restrict__ z, const float* __restrict__ cb,
                               const float* __restrict__ ce, const float* __restrict__ zn,
                               const int* __restrict__ cnt, const int* __restrict__ candV,
                               const float* __restrict__ candS,
                               int* __restrict__ idxb, float* __restrict__ out1) {
    int t = threadIdx.x;
    int lane = t & 63, wv = t >> 6;
    int pt = blockIdx.x * 4 + wv;
    int craw = cnt[pt];

    int b = pt >> 10, hw = pt & 1023;
    const float* zb = z + (size_t)b * (D_DIM * 1024) + hw;
    float A = zn[pt];
    float best = FLT_MAX; int bidx = 0x7fffffff;

    if (craw > CAND_CAP) {
        for (int code = lane; code < K_CB; code += 64) {
            const float* e = cb + (size_t)code * D_DIM;
            float dot = 0.f;
#pragma unroll 8
            for (int d = 0; d < D_DIM; ++d)
                dot = fmaf(zb[(size_t)d << 10], e[d], dot);
            float t1 = A + ce[code];
            float s = t1 - 2.0f * dot;
            if (s < best || (s == best && code < bidx)) { best = s; bidx = code; }
        }
    } else {
        int c = craw;
        float mn = FLT_MAX;
        for (int ci = lane; ci < c; ci += 64) mn = fminf(mn, candS[pt * CAND_CAP + ci]);
#pragma unroll
        for (int mk = 1; mk <= 32; mk <<= 1) mn = fminf(mn, __shfl_xor(mn, mk));
        float filt = mn + FILT;
        for (int ci = lane; ci < c; ci += 64) {
            float sa = candS[pt * CAND_CAP + ci];
            if (sa <= filt) {
                int code = candV[pt * CAND_CAP + ci];
                const float* e = cb + (size_t)code * D_DIM;
                float dot = 0.f;
#pragma unroll 8
                for (int d = 0; d < D_DIM; ++d)
                    dot = fmaf(zb[(size_t)d << 10], e[d], dot);   // sequential: BLAS order
                float t1 = A + ce[code];
                float s = t1 - 2.0f * dot;
                if (s < best || (s == best && code < bidx)) { best = s; bidx = code; }
            }
        }
    }
#pragma unroll
    for (int mk = 1; mk <= 32; mk <<= 1) {
        float ov = __shfl_xor(best, mk);
        int   oi = __shfl_xor(bidx, mk);
        if (ov < best || (ov == best && oi < bidx)) { best = ov; bidx = oi; }
    }
    if (lane == 0) { idxb[pt] = bidx; out1[pt] = (float)bidx; }
}

// ------------------------------------------- gather z_q, straight-through, loss
__global__ void gather_kernel(const float* __restrict__ z, const float* __restrict__ cb,
                              const int* __restrict__ idx, float* __restrict__ out0,
                              float* __restrict__ lsum) {
    int t = threadIdx.x;
    int e4 = blockIdx.x * 256 + t;
    int i = e4 * 4;
    int d = (i >> 10) & 255;
    int b = i >> 18;
    int nb = b * 1024 + (i & 1023);

    float4 zv = *reinterpret_cast<const float4*>(z + i);
    float4 o;
    float ls = 0.f;
    { int q = idx[nb + 0]; float e = cb[(size_t)q * D_DIM + d]; float df = e - zv.x; ls += df * df; o.x = zv.x + df; }
    { int q = idx[nb + 1]; float e = cb[(size_t)q * D_DIM + d]; float df = e - zv.y; ls += df * df; o.y = zv.y + df; }
    { int q = idx[nb + 2]; float e = cb[(size_t)q * D_DIM + d]; float df = e - zv.z; ls += df * df; o.z = zv.z + df; }
    { int q = idx[nb + 3]; float e = cb[(size_t)q * D_DIM + d]; float df = e - zv.w; ls += df * df; o.w = zv.w + df; }
    *reinterpret_cast<float4*>(out0 + i) = o;

#pragma unroll
    for (int off = 32; off >= 1; off >>= 1) ls += __shfl_down(ls, off);
    __shared__ float wsum[4];
    int lane = t & 63, w = t >> 6;
    if (lane == 0) wsum[w] = ls;
    __syncthreads();
    if (t == 0) atomicAdd(lsum, wsum[0] + wsum[1] + wsum[2] + wsum[3]);
}

__global__ void finalize_kernel(const float* __restrict__ lsum, float* __restrict__ out2) {
    out2[0] = 0.25f * lsum[0] / 4194304.0f;
}

// -----------------------------------------------------------------------------
extern "C" void kernel_launch(void* const* d_in, const int* in_sizes, int n_in,
                              void* d_out, int out_size, void* d_ws, size_t ws_size,
                              hipStream_t stream) {
    const float* z  = (const float*)d_in[0];
    const float* cb = (const float*)d_in[1];
    float* out  = (float*)d_out;
    float* out0 = out;
    float* out1 = out + 4194304;
    float* out2 = out + 4194304 + 16384;

    char* ws = (char*)d_ws;
    int*            cnt   = (int*)(ws);                          // 64 KB
    int*            candV = (int*)(ws + 65536);                  // 6 MB
    float*          candS = (float*)(ws + 6356992);              // 6 MB
    int*            idxb  = (int*)(ws + 12648448);               // 64 KB
    float*          ce    = (float*)(ws + 12713984);             // 32 KB
    float*          zn    = (float*)(ws + 12746752);             // 64 KB
    float*          lsum  = (float*)(ws + 12812288);             // 64 B
    unsigned short* cbb   = (unsigned short*)(ws + 12812352);    // 4 MB
    unsigned short* zT    = (unsigned short*)(ws + 17006656);    // 8 MB

    hipMemsetAsync(cnt, 0, 65536, stream);
    hipMemsetAsync(lsum, 0, 4, stream);
    pack_cb_kernel<<<(K_CB * D_DIM / 4) / 256, 256, 0, stream>>>(cb, cbb);
    pack_z_kernel<<<N_PTS / 64, 256, 0, stream>>>(z, zT);
    ce_kernel<<<K_CB / 4, 256, 0, stream>>>(cb, ce);
    zn_kernel<<<N_PTS / 256, 256, 0, stream>>>(z, zn);
    screen_kernel<<<dim3(N_PTS / 128, SPLITS), 512, 0, stream>>>(zT, cbb, ce, cnt, candV, candS);
    rescore_kernel<<<N_PTS / 4, 256, 0, stream>>>(z, cb, ce, zn, cnt, candV, candS, idxb, out1);
    gather_kernel<<<(N_PTS * D_DIM / 4) / 256, 256, 0, stream>>>(z, cb, idxb, out0, lsum);
    finalize_kernel<<<1, 1, 0, stream>>>(lsum, out2);
}

// Round 7
// 428.534 us; speedup vs baseline: 2.3789x; 1.1727x over previous
//
#include <hip/hip_runtime.h>
#include <float.h>

#define K_CB 8192
#define D_DIM 256
#define N_PTS 16384
#define SPLITS 16
#define CPS (K_CB / SPLITS)      // 512 codes per split-block
#define NTILES 4                 // 128-code n-tiles per block
#define CAND_CAP 96
#define CBUF_CAP 1536
#define MARGIN 3e-4f
#define FILT   1.2e-4f

typedef __attribute__((ext_vector_type(8))) short short8;
typedef __attribute__((ext_vector_type(4))) float f32x4;

__device__ __forceinline__ unsigned short f2bf(float x) {
    unsigned int u = __float_as_uint(x);
    u = u + 0x7fffu + ((u >> 16) & 1u);            // RNE
    return (unsigned short)(u >> 16);
}

__device__ __forceinline__ void gload16(const void* g, void* l) {
    __builtin_amdgcn_global_load_lds(
        (const __attribute__((address_space(1))) unsigned int*)g,
        (__attribute__((address_space(3))) unsigned int*)l, 16, 0, 0);
}

#define SBAR  __builtin_amdgcn_sched_barrier(0)
#define BARRIER __builtin_amdgcn_s_barrier()
#define WAIT_VM(n) asm volatile("s_waitcnt vmcnt(" #n ")" ::: "memory")
#define WAIT_LGKM0 asm volatile("s_waitcnt lgkmcnt(0)" ::: "memory")

// ---------------------------------------------------------------- ce = ||e||^2
__global__ void ce_kernel(const float* __restrict__ cb, float* __restrict__ ce) {
    int t = threadIdx.x;
    int lane = t & 63, w = t >> 6;
    int r = blockIdx.x * 4 + w;
    const float4 v = *reinterpret_cast<const float4*>(cb + (size_t)r * D_DIM + lane * 4);
    float s = v.x * v.x + v.y * v.y + v.z * v.z + v.w * v.w;
#pragma unroll
    for (int off = 32; off >= 1; off >>= 1) s += __shfl_down(s, off);
    if (lane == 0) ce[r] = s;
}

// ---------------------------------------------------------------- zn = ||z_n||^2
__global__ void zn_kernel(const float* __restrict__ z, float* __restrict__ zn) {
    int p = blockIdx.x * 256 + threadIdx.x;
    int b = p >> 10, hw = p & 1023;
    const float* base = z + (size_t)b * (D_DIM * 1024) + hw;
    float s = 0.f;
#pragma unroll 8
    for (int d = 0; d < D_DIM; ++d) {
        float v = base[(size_t)d * 1024];
        s = fmaf(v, v, s);
    }
    zn[p] = s;
}

// ---------------------------------------------------------------- cb -> bf16
__global__ void pack_cb_kernel(const float* __restrict__ cb, unsigned short* __restrict__ cbb) {
    int i = blockIdx.x * 256 + threadIdx.x;
    float4 v = reinterpret_cast<const float4*>(cb)[i];
    ushort4 o = { f2bf(v.x), f2bf(v.y), f2bf(v.z), f2bf(v.w) };
    reinterpret_cast<ushort4*>(cbb)[i] = o;
}

// -------------------------------------------- z (B,D,H,W) -> zT[pt][d] bf16
__global__ void pack_z_kernel(const float* __restrict__ z, unsigned short* __restrict__ zT) {
    __shared__ unsigned short tile[64 * 258];
    int t = threadIdx.x;
    int p0 = blockIdx.x * 64;
    int b = p0 >> 10, hw0 = p0 & 1023;
    const float* zb = z + (size_t)b * (D_DIM * 1024) + hw0;
    int ptl = t & 63, dq = t >> 6;
#pragma unroll 4
    for (int i = 0; i < 64; ++i) {
        int d = dq * 64 + i;
        float v = zb[(size_t)d * 1024 + ptl];
        tile[ptl * 258 + d] = f2bf(v);
    }
    __syncthreads();
    int pw = t >> 2, c0 = (t & 3) * 64;
    unsigned int* outp = reinterpret_cast<unsigned int*>(zT) + (((size_t)(p0 + pw) * D_DIM + c0) >> 1);
#pragma unroll 8
    for (int i = 0; i < 32; ++i) {
        unsigned int lo = tile[pw * 258 + c0 + 2 * i];
        unsigned int hi = tile[pw * 258 + c0 + 2 * i + 1];
        outp[i] = lo | (hi << 16);
    }
}

// --------------------------- MFMA screening v5: A-resident regs + B pipeline
//  + block-shared threshold (validated r3/r5 stats)
//  + LDS candidate staging (K-loop VMEM = staging loads ONLY -> counted vmcnt valid)
//  launch_bounds(512,2): this kernel NEEDS ~160 regs/wave (64 A-frag + 32 acc +
//  temporaries); capping at 4 waves/EU forces scratch spills (r6: 430MB WRITE_SIZE)
__global__ __launch_bounds__(512, 2)
void screen_kernel(const unsigned short* __restrict__ zT, const unsigned short* __restrict__ cbb,
                   const float* __restrict__ ce, int* __restrict__ cnt,
                   int* __restrict__ candV, float* __restrict__ candS) {
    __shared__ char sm[65536];        // union: A-stage [4][16KB] -> B ring bufs [4][16KB]
    __shared__ float pmin2[2][128];   // per-tile column mins
    __shared__ uint2 cbuf[CBUF_CAP];  // candidate staging: (ptl<<16|code, score-bits)
    __shared__ int ccnt;

    const int t = threadIdx.x;
    const int lane = t & 63, w = t >> 6;          // 8 waves
    const int wm = w >> 1, wn = w & 1;            // 4M x 2N
    const int g = lane >> 4, r = lane & 15;
    const int m0 = blockIdx.x * 128;
    const int c0s = blockIdx.y * CPS;
    const int lrow = lane >> 3;
    const int srcsw = (((lane & 7) ^ (lrow & 7)) << 4);   // pre-swizzled source byte
    const char* zTb = (const char*)zT;
    const char* cbB = (const char*)cbb;

    if (t == 0) ccnt = 0;

    // ---- preload ce for all epilogues (regs; keeps pipeline free of new loads)
    float ceR[NTILES][4];
#pragma unroll
    for (int nt = 0; nt < NTILES; ++nt)
#pragma unroll
        for (int f = 0; f < 4; ++f)
            ceR[nt][f] = ce[c0s + nt * 128 + wn * 64 + f * 16 + r];

    // ---- stage A (128 pts x 256 d bf16 = 64 KB), linear dest + pre-swz source
#pragma unroll
    for (int dc = 0; dc < 4; ++dc)
#pragma unroll
        for (int q = 0; q < 2; ++q) {
            int row = (w * 2 + q) * 8 + lrow;
            gload16(zTb + (size_t)(m0 + row) * 512 + dc * 128 + srcsw,
                    sm + dc * 16384 + (w * 2 + q) * 1024);
        }
    WAIT_VM(0);
    __syncthreads();                   // also fences the ccnt init

    // ---- A fragments into registers: a[m][kv], kv = dc*2+kk (64 VGPR)
    short8 a[2][8];
#pragma unroll
    for (int m = 0; m < 2; ++m)
#pragma unroll
        for (int kv = 0; kv < 8; ++kv) {
            int row = wm * 32 + m * 16 + r;
            a[m][kv] = *reinterpret_cast<const short8*>(
                sm + (kv >> 1) * 16384 + row * 128 + (((kv & 1) * 64 + g * 16) ^ ((row & 7) << 4)));
        }
    WAIT_LGKM0; SBAR; BARRIER; SBAR;   // all waves done reading A before B overwrites

#define STAGE_B(s_) do {                                                          \
        int nt_ = (s_) >> 2, dc_ = (s_) & 3;                                      \
        _Pragma("unroll")                                                         \
        for (int q = 0; q < 2; ++q) {                                             \
            int row = (w * 2 + q) * 8 + lrow;                                     \
            gload16(cbB + (size_t)(c0s + nt_ * 128 + row) * 512 + dc_ * 128 + srcsw, \
                    sm + dc_ * 16384 + (w * 2 + q) * 1024);                       \
        }                                                                         \
    } while (0)

    // ---- prologue: 3 stages in flight (6 loads/wave)
    STAGE_B(0); STAGE_B(1); STAGE_B(2);

    float rm[2][4];
#pragma unroll
    for (int m = 0; m < 2; ++m)
#pragma unroll
        for (int reg = 0; reg < 4; ++reg) rm[m][reg] = FLT_MAX;

#pragma unroll
    for (int nt = 0; nt < NTILES; ++nt) {
        f32x4 acc[2][4];
#pragma unroll
        for (int m = 0; m < 2; ++m)
#pragma unroll
            for (int f = 0; f < 4; ++f) acc[m][f] = (f32x4){0.f, 0.f, 0.f, 0.f};

#pragma unroll
        for (int dc = 0; dc < 4; ++dc) {
            const int s = nt * 4 + dc;
            if (s <= 13)      { WAIT_VM(4); }     // counted: 2 newer stages stay in flight
            else if (s == 14) { WAIT_VM(2); }
            else              { WAIT_VM(0); }
            SBAR; BARRIER; SBAR;
            if (s <= 12) STAGE_B(s + 3);          // refill ring buffer (s-1)&3

            // B fragments from buf dc
            short8 bfr[4][2];
#pragma unroll
            for (int f = 0; f < 4; ++f)
#pragma unroll
                for (int kk = 0; kk < 2; ++kk) {
                    int row = wn * 64 + f * 16 + r;
                    bfr[f][kk] = *reinterpret_cast<const short8*>(
                        sm + dc * 16384 + row * 128 + ((kk * 64 + g * 16) ^ ((row & 7) << 4)));
                }
            WAIT_LGKM0; SBAR;
            __builtin_amdgcn_s_setprio(1);
#pragma unroll
            for (int m = 0; m < 2; ++m)
#pragma unroll
                for (int f = 0; f < 4; ++f)
#pragma unroll
                    for (int kk = 0; kk < 2; ++kk)
                        acc[m][f] = __builtin_amdgcn_mfma_f32_16x16x32_bf16(
                            a[m][dc * 2 + kk], bfr[f][kk], acc[m][f], 0, 0, 0);
            __builtin_amdgcn_s_setprio(0);
        }

        // ---- epilogue: per-point tile-min, block-shared threshold (r3/r5 stats)
#pragma unroll
        for (int m = 0; m < 2; ++m)
#pragma unroll
            for (int reg = 0; reg < 4; ++reg) {
                float v = FLT_MAX;
#pragma unroll
                for (int f = 0; f < 4; ++f)
                    v = fminf(v, ceR[nt][f] - 2.f * acc[m][f][reg]);
                v = fminf(v, __shfl_xor(v, 1));
                v = fminf(v, __shfl_xor(v, 2));
                v = fminf(v, __shfl_xor(v, 4));
                v = fminf(v, __shfl_xor(v, 8));
                if (r == 0) pmin2[wn][wm * 32 + m * 16 + g * 4 + reg] = v;
            }
        WAIT_LGKM0; SBAR; BARRIER; SBAR;           // publish column mins
        float th[2][4];
#pragma unroll
        for (int m = 0; m < 2; ++m)
#pragma unroll
            for (int reg = 0; reg < 4; ++reg) {
                int ptl = wm * 32 + m * 16 + g * 4 + reg;
                rm[m][reg] = fminf(rm[m][reg], fminf(pmin2[0][ptl], pmin2[1][ptl]));
                th[m][reg] = rm[m][reg] + MARGIN;
            }
        // ---- collection into LDS staging (DS ops only: vmcnt untouched)
#pragma unroll
        for (int m = 0; m < 2; ++m)
#pragma unroll
            for (int f = 0; f < 4; ++f)
#pragma unroll
                for (int reg = 0; reg < 4; ++reg) {
                    float s_apx = ceR[nt][f] - 2.f * acc[m][f][reg];
                    if (s_apx <= th[m][reg]) {
                        int ptl = wm * 32 + m * 16 + g * 4 + reg;
                        int code = c0s + nt * 128 + wn * 64 + f * 16 + r;
                        int slot = atomicAdd(&ccnt, 1);
                        if (slot < CBUF_CAP)
                            cbuf[slot] = make_uint2(((unsigned)ptl << 16) | (unsigned)code,
                                                    __float_as_uint(s_apx));
                    }
                }
    }
#undef STAGE_B

    // ---- bulk flush to global (vmcnt-clean; after all pipelined stages)
    WAIT_LGKM0;
    __syncthreads();
    int total = ccnt;
    if (total > CBUF_CAP) {
        if (t < 128) atomicAdd(&cnt[m0 + t], 1000);    // poison -> full-scan fallback
    } else {
        for (int i = t; i < total; i += 512) {
            uint2 e = cbuf[i];
            int pt = m0 + (int)(e.x >> 16);
            int code = (int)(e.x & 0xffffu);
            int slot = atomicAdd(&cnt[pt], 1);
            if (slot < CAND_CAP) {
                candV[pt * CAND_CAP + slot] = code;
                candS[pt * CAND_CAP + slot] = __uint_as_float(e.y);
            }
        }
    }
}

// -------------- exact fp32 rescore (reference bit-semantics), approx-filtered,
//                with full-scan fallback on candidate-cap overflow
__global__ void rescore_kernel(const float* __restrict__ z, const float* __restrict__ cb,
                               const float* __restrict__ ce, const float* __restrict__ zn,
                               const int* __restrict__ cnt, const int* __restrict__ candV,
                               const float* __restrict__ candS,
                               int* __restrict__ idxb, float* __restrict__ out1) {
    int t = threadIdx.x;
    int lane = t & 63, wv = t >> 6;
    int pt = blockIdx.x * 4 + wv;
    int craw = cnt[pt];

    int b = pt >> 10, hw = pt & 1023;
    const float* zb = z + (size_t)b * (D_DIM * 1024) + hw;
    float A = zn[pt];
    float best = FLT_MAX; int bidx = 0x7fffffff;

    if (craw > CAND_CAP) {
        for (int code = lane; code < K_CB; code += 64) {
            const float* e = cb + (size_t)code * D_DIM;
            float dot = 0.f;
#pragma unroll 8
            for (int d = 0; d < D_DIM; ++d)
                dot = fmaf(zb[(size_t)d << 10], e[d], dot);
            float t1 = A + ce[code];
            float s = t1 - 2.0f * dot;
            if (s < best || (s == best && code < bidx)) { best = s; bidx = code; }
        }
    } else {
        int c = craw;
        float mn = FLT_MAX;
        for (int ci = lane; ci < c; ci += 64) mn = fminf(mn, candS[pt * CAND_CAP + ci]);
#pragma unroll
        for (int mk = 1; mk <= 32; mk <<= 1) mn = fminf(mn, __shfl_xor(mn, mk));
        float filt = mn + FILT;
        for (int ci = lane; ci < c; ci += 64) {
            float sa = candS[pt * CAND_CAP + ci];
            if (sa <= filt) {
                int code = candV[pt * CAND_CAP + ci];
                const float* e = cb + (size_t)code * D_DIM;
                float dot = 0.f;
#pragma unroll 8
                for (int d = 0; d < D_DIM; ++d)
                    dot = fmaf(zb[(size_t)d << 10], e[d], dot);   // sequential: BLAS order
                float t1 = A + ce[code];
                float s = t1 - 2.0f * dot;
                if (s < best || (s == best && code < bidx)) { best = s; bidx = code; }
            }
        }
    }
#pragma unroll
    for (int mk = 1; mk <= 32; mk <<= 1) {
        float ov = __shfl_xor(best, mk);
        int   oi = __shfl_xor(bidx, mk);
        if (ov < best || (ov == best && oi < bidx)) { best = ov; bidx = oi; }
    }
    if (lane == 0) { idxb[pt] = bidx; out1[pt] = (float)bidx; }
}

// ------------------------------------------- gather z_q, straight-through, loss
__global__ void gather_kernel(const float* __restrict__ z, const float* __restrict__ cb,
                              const int* __restrict__ idx, float* __restrict__ out0,
                              float* __restrict__ lsum) {
    int t = threadIdx.x;
    int e4 = blockIdx.x * 256 + t;
    int i = e4 * 4;
    int d = (i >> 10) & 255;
    int b = i >> 18;
    int nb = b * 1024 + (i & 1023);

    float4 zv = *reinterpret_cast<const float4*>(z + i);
    float4 o;
    float ls = 0.f;
    { int q = idx[nb + 0]; float e = cb[(size_t)q * D_DIM + d]; float df = e - zv.x; ls += df * df; o.x = zv.x + df; }
    { int q = idx[nb + 1]; float e = cb[(size_t)q * D_DIM + d]; float df = e - zv.y; ls += df * df; o.y = zv.y + df; }
    { int q = idx[nb + 2]; float e = cb[(size_t)q * D_DIM + d]; float df = e - zv.z; ls += df * df; o.z = zv.z + df; }
    { int q = idx[nb + 3]; float e = cb[(size_t)q * D_DIM + d]; float df = e - zv.w; ls += df * df; o.w = zv.w + df; }
    *reinterpret_cast<float4*>(out0 + i) = o;

#pragma unroll
    for (int off = 32; off >= 1; off >>= 1) ls += __shfl_down(ls, off);
    __shared__ float wsum[4];
    int lane = t & 63, w = t >> 6;
    if (lane == 0) wsum[w] = ls;
    __syncthreads();
    if (t == 0) atomicAdd(lsum, wsum[0] + wsum[1] + wsum[2] + wsum[3]);
}

__global__ void finalize_kernel(const float* __restrict__ lsum, float* __restrict__ out2) {
    out2[0] = 0.25f * lsum[0] / 4194304.0f;
}

// -----------------------------------------------------------------------------
extern "C" void kernel_launch(void* const* d_in, const int* in_sizes, int n_in,
                              void* d_out, int out_size, void* d_ws, size_t ws_size,
                              hipStream_t stream) {
    const float* z  = (const float*)d_in[0];
    const float* cb = (const float*)d_in[1];
    float* out  = (float*)d_out;
    float* out0 = out;
    float* out1 = out + 4194304;
    float* out2 = out + 4194304 + 16384;

    char* ws = (char*)d_ws;
    int*            cnt   = (int*)(ws);                          // 64 KB
    int*            candV = (int*)(ws + 65536);                  // 6 MB
    float*          candS = (float*)(ws + 6356992);              // 6 MB
    int*            idxb  = (int*)(ws + 12648448);               // 64 KB
    float*          ce    = (float*)(ws + 12713984);             // 32 KB
    float*          zn    = (float*)(ws + 12746752);             // 64 KB
    float*          lsum  = (float*)(ws + 12812288);             // 64 B
    unsigned short* cbb   = (unsigned short*)(ws + 12812352);    // 4 MB
    unsigned short* zT    = (unsigned short*)(ws + 17006656);    // 8 MB

    hipMemsetAsync(cnt, 0, 65536, stream);
    hipMemsetAsync(lsum, 0, 4, stream);
    pack_cb_kernel<<<(K_CB * D_DIM / 4) / 256, 256, 0, stream>>>(cb, cbb);
    pack_z_kernel<<<N_PTS / 64, 256, 0, stream>>>(z, zT);
    ce_kernel<<<K_CB / 4, 256, 0, stream>>>(cb, ce);
    zn_kernel<<<N_PTS / 256, 256, 0, stream>>>(z, zn);
    screen_kernel<<<dim3(N_PTS / 128, SPLITS), 512, 0, stream>>>(zT, cbb, ce, cnt, candV, candS);
    rescore_kernel<<<N_PTS / 4, 256, 0, stream>>>(z, cb, ce, zn, cnt, candV, candS, idxb, out1);
    gather_kernel<<<(N_PTS * D_DIM / 4) / 256, 256, 0, stream>>>(z, cb, idxb, out0, lsum);
    finalize_kernel<<<1, 1, 0, stream>>>(lsum, out2);
}